// Round 6
// baseline (311.513 us; speedup 1.0000x reference)
//
#include <hip/hip_runtime.h>

typedef unsigned short ushort_t;
typedef __attribute__((ext_vector_type(8))) short short8;
typedef __attribute__((ext_vector_type(4))) float f32x4;

// ---- bf16 helpers (RNE) ----
__device__ __forceinline__ ushort_t f2bf(float x) {
  union { float f; unsigned u; } v; v.f = x;
  unsigned r = v.u + 0x7fffu + ((v.u >> 16) & 1u);
  return (ushort_t)(r >> 16);
}
__device__ __forceinline__ float bf2f(ushort_t h) {
  union { unsigned u; float f; } v; v.u = ((unsigned)h) << 16;
  return v.f;
}

// ---- async global->LDS, 16B per lane, wave-uniform LDS base ----
__device__ __forceinline__ void async_cp16(const ushort_t* g, ushort_t* lds) {
  __builtin_amdgcn_global_load_lds(
      (const __attribute__((address_space(1))) unsigned int*)g,
      (__attribute__((address_space(3))) unsigned int*)lds, 16, 0, 0);
}

// =====================================================================
// NT GEMM core, double-buffered minimal 2-phase (T3-minimum recipe):
//   stage(0); per iter: __syncthreads() [its implicit vmcnt(0) waits on
//   loads issued one full compute phase ago -> ~free], then
//   stage(t+1 -> buf^1), compute(buf).
// Race-safety: at the barrier, all waves' ds_reads of buf^1 (from the
// previous compute) were already consumed by MFMAs (compiler drains
// lgkmcnt before use), so stage(t+1) may overwrite buf^1.
// One barrier per iteration; staging latency hidden behind compute.
//
// LDS XOR swizzle (verified r2: conflicts 4.4e7 -> ~0): linear LDS dest,
// pre-swizzled per-lane GLOBAL source seg^(row&7); fragment reads XOR
// seg with lm&7. Requires BKT=64 (8 segs/row) and RPC%8==0.
//
// EPI 1: store bf16 C. EPI 2: v = tan(acc*ip[row]*ic[col]), dual f32.
// =====================================================================
template <int MT, int NT, int BKT, int EPI>
__device__ __forceinline__ void gemm_core2(
    const ushort_t* __restrict__ A, int lda,
    const ushort_t* __restrict__ B, int ldb,
    int K,
    ushort_t* sA, ushort_t* sB,
    ushort_t* Cb, float* Cf0, float* Cf1, int ldc,
    const float* __restrict__ ip, const float* __restrict__ ic) {
  constexpr int MI = MT / 32, NI = NT / 32, KU = BKT / 32;
  constexpr int LPR = BKT / 8;    // 16B segs per staged row (must be 8)
  constexpr int RPC = 256 / LPR;  // rows per cp16 call
  constexpr int ASZ = MT * BKT, BSZ = NT * BKT;
  static_assert(LPR == 8, "swizzle assumes 8 segs per row");
  static_assert(RPC % 8 == 0, "row&7 must be per-lane constant");
  const int t = threadIdx.x;
  const int wave = t >> 6, lane = t & 63;
  const int lm = lane & 15, lq = lane >> 4;
  const int wr = wave >> 1, wc = wave & 1;

  f32x4 acc[MI][NI] = {};

  const int srow = t / LPR;
  const int gseg = (t % LPR) ^ (srow & 7);
  const ushort_t* ga = A + (size_t)srow * lda + gseg * 8;
  const ushort_t* gb = B + (size_t)srow * ldb + gseg * 8;
  const int sw = lm & 7;  // row&7 for fragment reads

  auto stage = [&](int k0, int buf) {
    ushort_t* dA = sA + buf * ASZ + wave * 512;
    ushort_t* dB = sB + buf * BSZ + wave * 512;
#pragma unroll
    for (int j = 0; j < MT / RPC; j++)
      async_cp16(ga + k0 + (size_t)j * RPC * lda, dA + j * 2048);
#pragma unroll
    for (int j = 0; j < NT / RPC; j++)
      async_cp16(gb + k0 + (size_t)j * RPC * ldb, dB + j * 2048);
  };

  stage(0, 0);
  int cur = 0;
  for (int k0 = 0; k0 < K; k0 += BKT) {
    __syncthreads();  // drains vmcnt for loads staged one iter ago (~free)
    if (k0 + BKT < K) stage(k0 + BKT, cur ^ 1);
    const ushort_t* cA = sA + cur * ASZ;
    const ushort_t* cB = sB + cur * BSZ;
#pragma unroll
    for (int ku = 0; ku < KU; ku++) {
      short8 af[MI], bf4[NI];
#pragma unroll
      for (int i = 0; i < MI; i++)
        af[i] = *(const short8*)(cA + (wr * (MT / 2) + i * 16 + lm) * BKT +
                                 ((ku * 4 + lq) ^ sw) * 8);
#pragma unroll
      for (int i = 0; i < NI; i++)
        bf4[i] = *(const short8*)(cB + (wc * (NT / 2) + i * 16 + lm) * BKT +
                                  ((ku * 4 + lq) ^ sw) * 8);
#pragma unroll
      for (int mt = 0; mt < MI; mt++)
#pragma unroll
        for (int nt = 0; nt < NI; nt++)
          acc[mt][nt] = __builtin_amdgcn_mfma_f32_16x16x32_bf16(
              af[mt], bf4[nt], acc[mt][nt], 0, 0, 0);
    }
    cur ^= 1;
  }

  // C/D layout (verified m89/m91): col = lane&15, row = (lane>>4)*4 + reg
#pragma unroll
  for (int mt = 0; mt < MI; mt++) {
    int rb = wr * (MT / 2) + mt * 16 + lq * 4;
#pragma unroll
    for (int nt = 0; nt < NI; nt++) {
      int c = wc * (NT / 2) + nt * 16 + lm;
#pragma unroll
      for (int r = 0; r < 4; r++) {
        size_t idx = (size_t)(rb + r) * ldc + c;
        if (EPI == 1) {
          Cb[idx] = f2bf(acc[mt][nt][r]);
        } else {
          float v = __tanf(acc[mt][nt][r] * ip[rb + r] * ic[c]);
          Cf0[idx] = v;
          Cf1[idx] = v;
        }
      }
    }
  }
}

// =====================================================================
// convT: 64x64 tile, read f32, write bf16 straight + bf16 transposed
// =====================================================================
__global__ __launch_bounds__(256) void convT(
    const float* __restrict__ in, ushort_t* __restrict__ outn,
    ushort_t* __restrict__ outt, int n) {
  __shared__ float tile[64][65];
  const int t = threadIdx.x;
  const int r0 = blockIdx.y * 64, c0 = blockIdx.x * 64;
  const int cr = t >> 4;        // 0..15
  const int cc = (t & 15) * 4;  // 0..60
#pragma unroll
  for (int p = 0; p < 4; p++) {
    int r = cr + p * 16;
    float4 v = *(const float4*)(in + (size_t)(r0 + r) * n + c0 + cc);
    tile[r][cc + 0] = v.x; tile[r][cc + 1] = v.y;
    tile[r][cc + 2] = v.z; tile[r][cc + 3] = v.w;
    ushort4 o;
    o.x = f2bf(v.x); o.y = f2bf(v.y); o.z = f2bf(v.z); o.w = f2bf(v.w);
    *(ushort4*)(outn + (size_t)(r0 + r) * n + c0 + cc) = o;
  }
  __syncthreads();
#pragma unroll
  for (int p = 0; p < 4; p++) {
    int r = cr + p * 16;  // output row = c0 + r
    ushort4 o;
    o.x = f2bf(tile[cc + 0][r]); o.y = f2bf(tile[cc + 1][r]);
    o.z = f2bf(tile[cc + 2][r]); o.w = f2bf(tile[cc + 3][r]);
    *(ushort4*)(outt + (size_t)(c0 + r) * n + r0 + cc) = o;
  }
}

// =====================================================================
// xcvt: concat(pre,cur) f32 [8192x512] -> bf16 xbf, 8 elems/thread
// =====================================================================
__global__ __launch_bounds__(256) void xcvt(
    const float* __restrict__ pre, const float* __restrict__ cur,
    ushort_t* __restrict__ xbf) {
  const size_t i = ((size_t)blockIdx.x * 256 + threadIdx.x) * 8;
  const float* src =
      (i < (size_t)4096 * 512) ? (pre + i) : (cur + (i - (size_t)4096 * 512));
  float4 a = *(const float4*)(src);
  float4 b = *(const float4*)(src + 4);
  short8 o;
  o[0] = (short)f2bf(a.x); o[1] = (short)f2bf(a.y);
  o[2] = (short)f2bf(a.z); o[3] = (short)f2bf(a.w);
  o[4] = (short)f2bf(b.x); o[5] = (short)f2bf(b.y);
  o[6] = (short)f2bf(b.z); o[7] = (short)f2bf(b.w);
  *(short8*)(xbf + i) = o;
}

// =====================================================================
// K1: pw_t[512 x 8192] = (concat(pre,cur) @ w)^T as NT GEMM.
// 64x128, BK=64, dbuf (48KB LDS, 2 blocks/CU), 512 blocks, 8 iters.
// =====================================================================
__global__ __launch_bounds__(256) void k1_gemm(
    const ushort_t* __restrict__ wt_t, const ushort_t* __restrict__ xbf,
    ushort_t* __restrict__ pw_t) {
  __shared__ __align__(16) ushort_t sA[2 * 64 * 64];
  __shared__ __align__(16) ushort_t sB[2 * 128 * 64];
  const int bm = blockIdx.x & 7, bn = blockIdx.x >> 3;
  const ushort_t* A = wt_t + (size_t)bm * 64 * 512;
  const ushort_t* B = xbf + (size_t)bn * 128 * 512;
  ushort_t* C = pw_t + (size_t)bm * 64 * 8192 + bn * 128;
  gemm_core2<64, 128, 64, 1>(A, 512, B, 512, 512, sA, sB, C, nullptr, nullptr,
                             8192, nullptr, nullptr);
}

// =====================================================================
// K2 fused: half0 pre_h = adj @ cur_w ; half1 cur_h = adj^T @ pre_w
// 128x64 tiles, BK=64, dbuf (48KB LDS, 2 blocks/CU), 512 blocks, 64 iters.
// =====================================================================
__global__ __launch_bounds__(256) void k2_gemm(
    const ushort_t* __restrict__ adj, const ushort_t* __restrict__ adj_t,
    const ushort_t* __restrict__ pw_t, ushort_t* __restrict__ pn) {
  __shared__ __align__(16) ushort_t sA[2 * 128 * 64];
  __shared__ __align__(16) ushort_t sB[2 * 64 * 64];
  const int b = blockIdx.x;
  const int xcd = b & 7, i = b >> 3;            // i in 0..63
  const int half = xcd & 1;
  const int bm = ((xcd >> 1) << 3) | (i & 7);   // 0..31
  const int bn = i >> 3;                        // 0..7
  const ushort_t* A = (half ? adj_t : adj) + (size_t)bm * 128 * 4096;
  const ushort_t* B = pw_t + (size_t)bn * 64 * 8192 + (half ? 0 : 4096);
  ushort_t* C = pn + (half ? (size_t)4096 * 512 : 0) +
                (size_t)bm * 128 * 512 + bn * 64;
  gemm_core2<128, 64, 64, 1>(A, 4096, B, 8192, 4096, sA, sB, C, nullptr,
                             nullptr, 512, nullptr, nullptr);
}

// =====================================================================
// invnorm: invn[row] = 1 / max(||pn[row]||, 1e-8), one wave per row
// =====================================================================
__global__ __launch_bounds__(256) void invnorm_kernel(
    const ushort_t* __restrict__ pn, float* __restrict__ invn) {
  const int t = threadIdx.x;
  const int wave = t >> 6, lane = t & 63;
  const size_t row = (size_t)blockIdx.x * 4 + wave;
  const ushort_t* p = pn + row * 512 + lane * 8;
  short8 v = *(const short8*)p;
  float s = 0.f;
#pragma unroll
  for (int i = 0; i < 8; i++) {
    float f = bf2f((ushort_t)v[i]);
    s += f * f;
  }
#pragma unroll
  for (int off = 32; off > 0; off >>= 1) s += __shfl_xor(s, off, 64);
  if (lane == 0) invn[row] = 1.0f / fmaxf(sqrtf(s), 1e-8f);
}

// =====================================================================
// K3: cos = (pre_h @ cur_h^T) * inv_i * inv_j, tan, dual f32 store.
// 128x128, BK=64, dbuf (64KB LDS, 2 blocks/CU), 1024 blocks, 8 iters.
// =====================================================================
__global__ __launch_bounds__(256) void k3_gemm(
    const ushort_t* __restrict__ pn, const float* __restrict__ invn,
    float* __restrict__ out) {
  __shared__ __align__(16) ushort_t sA[2 * 128 * 64];
  __shared__ __align__(16) ushort_t sB[2 * 128 * 64];
  const int bm = blockIdx.x & 31, bn = blockIdx.x >> 5;
  const ushort_t* A = pn + (size_t)bm * 128 * 512;
  const ushort_t* B = pn + (size_t)4096 * 512 + (size_t)bn * 128 * 512;
  float* C0 = out + (size_t)bm * 128 * 4096 + bn * 128;
  gemm_core2<128, 128, 64, 2>(A, 512, B, 512, 512, sA, sB, nullptr, C0,
                              C0 + (size_t)4096 * 4096, 4096,
                              invn + bm * 128, invn + 4096 + bn * 128);
}

// =====================================================================
extern "C" void kernel_launch(void* const* d_in, const int* in_sizes, int n_in,
                              void* d_out, int out_size, void* d_ws,
                              size_t ws_size, hipStream_t stream) {
  const float* pre = (const float*)d_in[0];   // [4096,512] f32
  const float* cur = (const float*)d_in[1];   // [4096,512] f32
  const float* adj = (const float*)d_in[2];   // [4096,4096] f32
  const float* wt  = (const float*)d_in[3];   // [512,512] f32
  float* out = (float*)d_out;                 // 2 x [4096,4096] f32

  // workspace layout (~93 MB)
  ushort_t* adj_bf = (ushort_t*)d_ws;                       // 4096*4096
  ushort_t* adj_t  = adj_bf + (size_t)4096 * 4096;          // 4096*4096
  ushort_t* pw_t   = adj_t + (size_t)4096 * 4096;           // 512*8192
  ushort_t* pn     = pw_t + (size_t)512 * 8192;             // 8192*512
  ushort_t* wt_t   = pn + (size_t)8192 * 512;               // 512*512
  ushort_t* wt_bf  = wt_t + (size_t)512 * 512;              // 512*512 (dummy)
  float*    invn   = (float*)(wt_bf + (size_t)512 * 512);   // 8192 f32
  ushort_t* xbf    = (ushort_t*)(invn + 8192);              // 8192*512

  convT<<<dim3(64, 64), 256, 0, stream>>>(adj, adj_bf, adj_t, 4096);
  convT<<<dim3(8, 8), 256, 0, stream>>>(wt, wt_bf, wt_t, 512);
  xcvt<<<2048, 256, 0, stream>>>(pre, cur, xbf);
  k1_gemm<<<512, 256, 0, stream>>>(wt_t, xbf, pw_t);
  k2_gemm<<<512, 256, 0, stream>>>(adj_bf, adj_t, pw_t, pn);
  invnorm_kernel<<<2048, 256, 0, stream>>>(pn, invn);
  k3_gemm<<<1024, 256, 0, stream>>>(pn, invn, out);
}

// Round 7
// 305.829 us; speedup vs baseline: 1.0186x; 1.0186x over previous
//
#include <hip/hip_runtime.h>

typedef unsigned short ushort_t;
typedef __attribute__((ext_vector_type(8))) short short8;
typedef __attribute__((ext_vector_type(4))) float f32x4;

// ---- bf16 helpers (RNE) ----
__device__ __forceinline__ ushort_t f2bf(float x) {
  union { float f; unsigned u; } v; v.f = x;
  unsigned r = v.u + 0x7fffu + ((v.u >> 16) & 1u);
  return (ushort_t)(r >> 16);
}
__device__ __forceinline__ float bf2f(ushort_t h) {
  union { unsigned u; float f; } v; v.u = ((unsigned)h) << 16;
  return v.f;
}

// ---- async global->LDS, 16B per lane, wave-uniform LDS base ----
__device__ __forceinline__ void async_cp16(const ushort_t* g, ushort_t* lds) {
  __builtin_amdgcn_global_load_lds(
      (const __attribute__((address_space(1))) unsigned int*)g,
      (__attribute__((address_space(3))) unsigned int*)lds, 16, 0, 0);
}

// =====================================================================
// gemm_core3: counted-vmcnt triple-buffered NT GEMM (T4 minimal form).
//   stage(0); per iter s: stage(s+1) [6 loads], s_waitcnt vmcnt(6)
//   [waits ONLY stage(s); stage(s+1) stays in flight ACROSS the
//   barrier], raw s_barrier, compute(buf[s%3]).
// Race ledger (verified by skew analysis): one barrier/iter bounds wave
// skew to 1 iteration; writer buf[(s+1)%3] vs any concurrent reader
// buf[(s-1)%3] or buf[s%3]: index diff in {1,2} mod 3, never 0.
// vmcnt FIFO: <=6 outstanding => the 6 oldest (stage s) retired; each
// wave waits BEFORE the barrier => all waves' chunks complete after it.
// Requires exactly 6 global_load_lds per stage: MT/RPC + NT/RPC == 6.
//
// LDS XOR swizzle (verified r2: conflicts 4.4e7 -> ~0): linear LDS dest,
// pre-swizzled per-lane GLOBAL source seg^(row&7); fragment reads XOR
// seg with lm&7. Requires BKT=64 (8 segs/row) and RPC%8==0.
// =====================================================================
template <int MT, int NT, int BKT, int EPI>
__device__ __forceinline__ void gemm_core3(
    const ushort_t* __restrict__ A, int lda,
    const ushort_t* __restrict__ B, int ldb,
    int K,
    ushort_t* sA, ushort_t* sB,
    ushort_t* Cb, float* Cf0, float* Cf1, int ldc,
    const float* __restrict__ ip, const float* __restrict__ ic) {
  constexpr int MI = MT / 32, NI = NT / 32, KU = BKT / 32;
  constexpr int LPR = BKT / 8;    // 16B segs per staged row (must be 8)
  constexpr int RPC = 256 / LPR;  // rows per cp16 call
  constexpr int ASZ = MT * BKT, BSZ = NT * BKT;
  static_assert(LPR == 8, "swizzle assumes 8 segs per row");
  static_assert(RPC % 8 == 0, "row&7 must be per-lane constant");
  static_assert(MT / RPC + NT / RPC == 6, "vmcnt(6) assumes 6 loads/stage");
  const int t = threadIdx.x;
  const int wave = t >> 6, lane = t & 63;
  const int lm = lane & 15, lq = lane >> 4;
  const int wr = wave >> 1, wc = wave & 1;

  f32x4 acc[MI][NI] = {};

  const int srow = t / LPR;
  const int gseg = (t % LPR) ^ (srow & 7);
  const ushort_t* ga = A + (size_t)srow * lda + gseg * 8;
  const ushort_t* gb = B + (size_t)srow * ldb + gseg * 8;
  const int sw = lm & 7;  // row&7 for fragment reads

  auto stage = [&](int k0, int buf) {
    ushort_t* dA = sA + buf * ASZ + wave * 512;
    ushort_t* dB = sB + buf * BSZ + wave * 512;
#pragma unroll
    for (int j = 0; j < MT / RPC; j++)
      async_cp16(ga + k0 + (size_t)j * RPC * lda, dA + j * 2048);
#pragma unroll
    for (int j = 0; j < NT / RPC; j++)
      async_cp16(gb + k0 + (size_t)j * RPC * ldb, dB + j * 2048);
  };

  const int NSTEP = K / BKT;
  stage(0, 0);
  int cur = 0, nxt = 1;
  for (int s = 0; s < NSTEP; ++s) {
    if (s + 1 < NSTEP) {
      stage((s + 1) * BKT, nxt);
      asm volatile("s_waitcnt vmcnt(6)" ::: "memory");
    } else {
      asm volatile("s_waitcnt vmcnt(0)" ::: "memory");
    }
    __builtin_amdgcn_s_barrier();
    const ushort_t* cA = sA + cur * ASZ;
    const ushort_t* cB = sB + cur * BSZ;
#pragma unroll
    for (int ku = 0; ku < KU; ku++) {
      short8 af[MI], bf4[NI];
#pragma unroll
      for (int i = 0; i < MI; i++)
        af[i] = *(const short8*)(cA + (wr * (MT / 2) + i * 16 + lm) * BKT +
                                 ((ku * 4 + lq) ^ sw) * 8);
#pragma unroll
      for (int i = 0; i < NI; i++)
        bf4[i] = *(const short8*)(cB + (wc * (NT / 2) + i * 16 + lm) * BKT +
                                  ((ku * 4 + lq) ^ sw) * 8);
#pragma unroll
      for (int mt = 0; mt < MI; mt++)
#pragma unroll
        for (int nt = 0; nt < NI; nt++)
          acc[mt][nt] = __builtin_amdgcn_mfma_f32_16x16x32_bf16(
              af[mt], bf4[nt], acc[mt][nt], 0, 0, 0);
    }
    cur = nxt;
    nxt = (nxt == 2) ? 0 : nxt + 1;
  }

  // C/D layout (verified m89/m91): col = lane&15, row = (lane>>4)*4 + reg
#pragma unroll
  for (int mt = 0; mt < MI; mt++) {
    int rb = wr * (MT / 2) + mt * 16 + lq * 4;
#pragma unroll
    for (int nt = 0; nt < NI; nt++) {
      int c = wc * (NT / 2) + nt * 16 + lm;
#pragma unroll
      for (int r = 0; r < 4; r++) {
        size_t idx = (size_t)(rb + r) * ldc + c;
        if (EPI == 1) {
          Cb[idx] = f2bf(acc[mt][nt][r]);
        } else {
          float v = __tanf(acc[mt][nt][r] * ip[rb + r] * ic[c]);
          Cf0[idx] = v;
          Cf1[idx] = v;
        }
      }
    }
  }
}

// =====================================================================
// gemm_core2: double-buffered 2-phase via __syncthreads (known-good r6).
// Used by k3 only this round (blast-radius control).
// =====================================================================
template <int MT, int NT, int BKT, int EPI>
__device__ __forceinline__ void gemm_core2(
    const ushort_t* __restrict__ A, int lda,
    const ushort_t* __restrict__ B, int ldb,
    int K,
    ushort_t* sA, ushort_t* sB,
    ushort_t* Cb, float* Cf0, float* Cf1, int ldc,
    const float* __restrict__ ip, const float* __restrict__ ic) {
  constexpr int MI = MT / 32, NI = NT / 32, KU = BKT / 32;
  constexpr int LPR = BKT / 8;
  constexpr int RPC = 256 / LPR;
  constexpr int ASZ = MT * BKT, BSZ = NT * BKT;
  static_assert(LPR == 8, "swizzle assumes 8 segs per row");
  static_assert(RPC % 8 == 0, "row&7 must be per-lane constant");
  const int t = threadIdx.x;
  const int wave = t >> 6, lane = t & 63;
  const int lm = lane & 15, lq = lane >> 4;
  const int wr = wave >> 1, wc = wave & 1;

  f32x4 acc[MI][NI] = {};

  const int srow = t / LPR;
  const int gseg = (t % LPR) ^ (srow & 7);
  const ushort_t* ga = A + (size_t)srow * lda + gseg * 8;
  const ushort_t* gb = B + (size_t)srow * ldb + gseg * 8;
  const int sw = lm & 7;

  auto stage = [&](int k0, int buf) {
    ushort_t* dA = sA + buf * ASZ + wave * 512;
    ushort_t* dB = sB + buf * BSZ + wave * 512;
#pragma unroll
    for (int j = 0; j < MT / RPC; j++)
      async_cp16(ga + k0 + (size_t)j * RPC * lda, dA + j * 2048);
#pragma unroll
    for (int j = 0; j < NT / RPC; j++)
      async_cp16(gb + k0 + (size_t)j * RPC * ldb, dB + j * 2048);
  };

  stage(0, 0);
  int cur = 0;
  for (int k0 = 0; k0 < K; k0 += BKT) {
    __syncthreads();
    if (k0 + BKT < K) stage(k0 + BKT, cur ^ 1);
    const ushort_t* cA = sA + cur * ASZ;
    const ushort_t* cB = sB + cur * BSZ;
#pragma unroll
    for (int ku = 0; ku < KU; ku++) {
      short8 af[MI], bf4[NI];
#pragma unroll
      for (int i = 0; i < MI; i++)
        af[i] = *(const short8*)(cA + (wr * (MT / 2) + i * 16 + lm) * BKT +
                                 ((ku * 4 + lq) ^ sw) * 8);
#pragma unroll
      for (int i = 0; i < NI; i++)
        bf4[i] = *(const short8*)(cB + (wc * (NT / 2) + i * 16 + lm) * BKT +
                                  ((ku * 4 + lq) ^ sw) * 8);
#pragma unroll
      for (int mt = 0; mt < MI; mt++)
#pragma unroll
        for (int nt = 0; nt < NI; nt++)
          acc[mt][nt] = __builtin_amdgcn_mfma_f32_16x16x32_bf16(
              af[mt], bf4[nt], acc[mt][nt], 0, 0, 0);
    }
    cur ^= 1;
  }

#pragma unroll
  for (int mt = 0; mt < MI; mt++) {
    int rb = wr * (MT / 2) + mt * 16 + lq * 4;
#pragma unroll
    for (int nt = 0; nt < NI; nt++) {
      int c = wc * (NT / 2) + nt * 16 + lm;
#pragma unroll
      for (int r = 0; r < 4; r++) {
        size_t idx = (size_t)(rb + r) * ldc + c;
        if (EPI == 1) {
          Cb[idx] = f2bf(acc[mt][nt][r]);
        } else {
          float v = __tanf(acc[mt][nt][r] * ip[rb + r] * ic[c]);
          Cf0[idx] = v;
          Cf1[idx] = v;
        }
      }
    }
  }
}

// =====================================================================
// convT: 64x64 tile, read f32, write bf16 straight + bf16 transposed
// =====================================================================
__global__ __launch_bounds__(256) void convT(
    const float* __restrict__ in, ushort_t* __restrict__ outn,
    ushort_t* __restrict__ outt, int n) {
  __shared__ float tile[64][65];
  const int t = threadIdx.x;
  const int r0 = blockIdx.y * 64, c0 = blockIdx.x * 64;
  const int cr = t >> 4;        // 0..15
  const int cc = (t & 15) * 4;  // 0..60
#pragma unroll
  for (int p = 0; p < 4; p++) {
    int r = cr + p * 16;
    float4 v = *(const float4*)(in + (size_t)(r0 + r) * n + c0 + cc);
    tile[r][cc + 0] = v.x; tile[r][cc + 1] = v.y;
    tile[r][cc + 2] = v.z; tile[r][cc + 3] = v.w;
    ushort4 o;
    o.x = f2bf(v.x); o.y = f2bf(v.y); o.z = f2bf(v.z); o.w = f2bf(v.w);
    *(ushort4*)(outn + (size_t)(r0 + r) * n + c0 + cc) = o;
  }
  __syncthreads();
#pragma unroll
  for (int p = 0; p < 4; p++) {
    int r = cr + p * 16;  // output row = c0 + r
    ushort4 o;
    o.x = f2bf(tile[cc + 0][r]); o.y = f2bf(tile[cc + 1][r]);
    o.z = f2bf(tile[cc + 2][r]); o.w = f2bf(tile[cc + 3][r]);
    *(ushort4*)(outt + (size_t)(c0 + r) * n + r0 + cc) = o;
  }
}

// =====================================================================
// xcvt: concat(pre,cur) f32 [8192x512] -> bf16 xbf, 8 elems/thread
// =====================================================================
__global__ __launch_bounds__(256) void xcvt(
    const float* __restrict__ pre, const float* __restrict__ cur,
    ushort_t* __restrict__ xbf) {
  const size_t i = ((size_t)blockIdx.x * 256 + threadIdx.x) * 8;
  const float* src =
      (i < (size_t)4096 * 512) ? (pre + i) : (cur + (i - (size_t)4096 * 512));
  float4 a = *(const float4*)(src);
  float4 b = *(const float4*)(src + 4);
  short8 o;
  o[0] = (short)f2bf(a.x); o[1] = (short)f2bf(a.y);
  o[2] = (short)f2bf(a.z); o[3] = (short)f2bf(a.w);
  o[4] = (short)f2bf(b.x); o[5] = (short)f2bf(b.y);
  o[6] = (short)f2bf(b.z); o[7] = (short)f2bf(b.w);
  *(short8*)(xbf + i) = o;
}

// =====================================================================
// K1: pw_t[512 x 8192] = (concat(pre,cur) @ w)^T as NT GEMM.
// 64x128, BK=64, counted-vmcnt tbuf (72KB LDS, 2 blocks/CU), 512 blocks.
// =====================================================================
__global__ __launch_bounds__(256) void k1_gemm(
    const ushort_t* __restrict__ wt_t, const ushort_t* __restrict__ xbf,
    ushort_t* __restrict__ pw_t) {
  __shared__ __align__(16) ushort_t sA[3 * 64 * 64];
  __shared__ __align__(16) ushort_t sB[3 * 128 * 64];
  const int bm = blockIdx.x & 7, bn = blockIdx.x >> 3;
  const ushort_t* A = wt_t + (size_t)bm * 64 * 512;
  const ushort_t* B = xbf + (size_t)bn * 128 * 512;
  ushort_t* C = pw_t + (size_t)bm * 64 * 8192 + bn * 128;
  gemm_core3<64, 128, 64, 1>(A, 512, B, 512, 512, sA, sB, C, nullptr, nullptr,
                             8192, nullptr, nullptr);
}

// =====================================================================
// K2 fused: half0 pre_h = adj @ cur_w ; half1 cur_h = adj^T @ pre_w
// 128x64, BK=64, counted-vmcnt tbuf (72KB LDS, 2 blocks/CU), 512 blocks.
// =====================================================================
__global__ __launch_bounds__(256) void k2_gemm(
    const ushort_t* __restrict__ adj, const ushort_t* __restrict__ adj_t,
    const ushort_t* __restrict__ pw_t, ushort_t* __restrict__ pn) {
  __shared__ __align__(16) ushort_t sA[3 * 128 * 64];
  __shared__ __align__(16) ushort_t sB[3 * 64 * 64];
  const int b = blockIdx.x;
  const int xcd = b & 7, i = b >> 3;            // i in 0..63
  const int half = xcd & 1;
  const int bm = ((xcd >> 1) << 3) | (i & 7);   // 0..31
  const int bn = i >> 3;                        // 0..7
  const ushort_t* A = (half ? adj_t : adj) + (size_t)bm * 128 * 4096;
  const ushort_t* B = pw_t + (size_t)bn * 64 * 8192 + (half ? 0 : 4096);
  ushort_t* C = pn + (half ? (size_t)4096 * 512 : 0) +
                (size_t)bm * 128 * 512 + bn * 64;
  gemm_core3<128, 64, 64, 1>(A, 4096, B, 8192, 4096, sA, sB, C, nullptr,
                             nullptr, 512, nullptr, nullptr);
}

// =====================================================================
// invnorm: invn[row] = 1 / max(||pn[row]||, 1e-8), one wave per row
// =====================================================================
__global__ __launch_bounds__(256) void invnorm_kernel(
    const ushort_t* __restrict__ pn, float* __restrict__ invn) {
  const int t = threadIdx.x;
  const int wave = t >> 6, lane = t & 63;
  const size_t row = (size_t)blockIdx.x * 4 + wave;
  const ushort_t* p = pn + row * 512 + lane * 8;
  short8 v = *(const short8*)p;
  float s = 0.f;
#pragma unroll
  for (int i = 0; i < 8; i++) {
    float f = bf2f((ushort_t)v[i]);
    s += f * f;
  }
#pragma unroll
  for (int off = 32; off > 0; off >>= 1) s += __shfl_xor(s, off, 64);
  if (lane == 0) invn[row] = 1.0f / fmaxf(sqrtf(s), 1e-8f);
}

// =====================================================================
// K3: cos = (pre_h @ cur_h^T) * inv_i * inv_j, tan, dual f32 store.
// 128x128, BK=64, dbuf (64KB LDS, 2 blocks/CU), 1024 blocks. (r6 core)
// =====================================================================
__global__ __launch_bounds__(256) void k3_gemm(
    const ushort_t* __restrict__ pn, const float* __restrict__ invn,
    float* __restrict__ out) {
  __shared__ __align__(16) ushort_t sA[2 * 128 * 64];
  __shared__ __align__(16) ushort_t sB[2 * 128 * 64];
  const int bm = blockIdx.x & 31, bn = blockIdx.x >> 5;
  const ushort_t* A = pn + (size_t)bm * 128 * 512;
  const ushort_t* B = pn + (size_t)4096 * 512 + (size_t)bn * 128 * 512;
  float* C0 = out + (size_t)bm * 128 * 4096 + bn * 128;
  gemm_core2<128, 128, 64, 2>(A, 512, B, 512, 512, sA, sB, nullptr, C0,
                              C0 + (size_t)4096 * 4096, 4096,
                              invn + bm * 128, invn + 4096 + bn * 128);
}

// =====================================================================
extern "C" void kernel_launch(void* const* d_in, const int* in_sizes, int n_in,
                              void* d_out, int out_size, void* d_ws,
                              size_t ws_size, hipStream_t stream) {
  const float* pre = (const float*)d_in[0];   // [4096,512] f32
  const float* cur = (const float*)d_in[1];   // [4096,512] f32
  const float* adj = (const float*)d_in[2];   // [4096,4096] f32
  const float* wt  = (const float*)d_in[3];   // [512,512] f32
  float* out = (float*)d_out;                 // 2 x [4096,4096] f32

  // workspace layout (~93 MB)
  ushort_t* adj_bf = (ushort_t*)d_ws;                       // 4096*4096
  ushort_t* adj_t  = adj_bf + (size_t)4096 * 4096;          // 4096*4096
  ushort_t* pw_t   = adj_t + (size_t)4096 * 4096;           // 512*8192
  ushort_t* pn     = pw_t + (size_t)512 * 8192;             // 8192*512
  ushort_t* wt_t   = pn + (size_t)8192 * 512;               // 512*512
  ushort_t* wt_bf  = wt_t + (size_t)512 * 512;              // 512*512 (dummy)
  float*    invn   = (float*)(wt_bf + (size_t)512 * 512);   // 8192 f32
  ushort_t* xbf    = (ushort_t*)(invn + 8192);              // 8192*512

  convT<<<dim3(64, 64), 256, 0, stream>>>(adj, adj_bf, adj_t, 4096);
  convT<<<dim3(8, 8), 256, 0, stream>>>(wt, wt_bf, wt_t, 512);
  xcvt<<<2048, 256, 0, stream>>>(pre, cur, xbf);
  k1_gemm<<<512, 256, 0, stream>>>(wt_t, xbf, pw_t);
  k2_gemm<<<512, 256, 0, stream>>>(adj_bf, adj_t, pw_t, pn);
  invnorm_kernel<<<2048, 256, 0, stream>>>(pn, invn);
  k3_gemm<<<1024, 256, 0, stream>>>(pn, invn, out);
}

// Round 8
// 300.599 us; speedup vs baseline: 1.0363x; 1.0174x over previous
//
#include <hip/hip_runtime.h>

typedef unsigned short ushort_t;
typedef __attribute__((ext_vector_type(8))) short short8;
typedef __attribute__((ext_vector_type(4))) float f32x4;

// ---- bf16 helpers (RNE) ----
__device__ __forceinline__ ushort_t f2bf(float x) {
  union { float f; unsigned u; } v; v.f = x;
  unsigned r = v.u + 0x7fffu + ((v.u >> 16) & 1u);
  return (ushort_t)(r >> 16);
}
__device__ __forceinline__ float bf2f(ushort_t h) {
  union { unsigned u; float f; } v; v.u = ((unsigned)h) << 16;
  return v.f;
}

// ---- async global->LDS, 16B per lane, wave-uniform LDS base ----
__device__ __forceinline__ void async_cp16(const ushort_t* g, ushort_t* lds) {
  __builtin_amdgcn_global_load_lds(
      (const __attribute__((address_space(1))) unsigned int*)g,
      (__attribute__((address_space(3))) unsigned int*)lds, 16, 0, 0);
}

// =====================================================================
// gemm_core3: counted-vmcnt triple-buffered NT GEMM (T4 minimal form).
// Per iter s: stage(s+1) [6 loads], s_waitcnt vmcnt(6) [waits ONLY
// stage(s); stage(s+1) stays in flight ACROSS the barrier], raw
// s_barrier, compute(buf[s%3]).
// Race ledger: one barrier/iter bounds wave skew to 1 iteration; writer
// buf[(s+1)%3] vs concurrent readers buf[s%3]/buf[(s-1)%3]: index diff
// {1,2} mod 3, never 0. vmcnt FIFO: <=6 outstanding => 6 oldest retired;
// each wave waits BEFORE the barrier => chunks complete after it.
//
// LDS XOR swizzle (verified r2: conflicts 4.4e7 -> ~0): linear LDS dest,
// pre-swizzled per-lane GLOBAL source seg^(row&7); fragment reads XOR
// seg with lm&7. Requires BKT=64 (8 segs/row) and RPC%8==0.
// =====================================================================
template <int MT, int NT, int BKT, int EPI>
__device__ __forceinline__ void gemm_core3(
    const ushort_t* __restrict__ A, int lda,
    const ushort_t* __restrict__ B, int ldb,
    int K,
    ushort_t* sA, ushort_t* sB,
    ushort_t* Cb, float* Cf0, float* Cf1, int ldc,
    const float* __restrict__ ip, const float* __restrict__ ic) {
  constexpr int MI = MT / 32, NI = NT / 32, KU = BKT / 32;
  constexpr int LPR = BKT / 8;    // 16B segs per staged row (must be 8)
  constexpr int RPC = 256 / LPR;  // rows per cp16 call
  constexpr int ASZ = MT * BKT, BSZ = NT * BKT;
  static_assert(LPR == 8, "swizzle assumes 8 segs per row");
  static_assert(RPC % 8 == 0, "row&7 must be per-lane constant");
  static_assert(MT / RPC + NT / RPC == 6, "vmcnt(6) assumes 6 loads/stage");
  const int t = threadIdx.x;
  const int wave = t >> 6, lane = t & 63;
  const int lm = lane & 15, lq = lane >> 4;
  const int wr = wave >> 1, wc = wave & 1;

  f32x4 acc[MI][NI] = {};

  const int srow = t / LPR;
  const int gseg = (t % LPR) ^ (srow & 7);
  const ushort_t* ga = A + (size_t)srow * lda + gseg * 8;
  const ushort_t* gb = B + (size_t)srow * ldb + gseg * 8;
  const int sw = lm & 7;  // row&7 for fragment reads

  auto stage = [&](int k0, int buf) {
    ushort_t* dA = sA + buf * ASZ + wave * 512;
    ushort_t* dB = sB + buf * BSZ + wave * 512;
#pragma unroll
    for (int j = 0; j < MT / RPC; j++)
      async_cp16(ga + k0 + (size_t)j * RPC * lda, dA + j * 2048);
#pragma unroll
    for (int j = 0; j < NT / RPC; j++)
      async_cp16(gb + k0 + (size_t)j * RPC * ldb, dB + j * 2048);
  };

  const int NSTEP = K / BKT;
  stage(0, 0);
  int cur = 0, nxt = 1;
  for (int s = 0; s < NSTEP; ++s) {
    if (s + 1 < NSTEP) {
      stage((s + 1) * BKT, nxt);
      asm volatile("s_waitcnt vmcnt(6)" ::: "memory");
    } else {
      asm volatile("s_waitcnt vmcnt(0)" ::: "memory");
    }
    __builtin_amdgcn_s_barrier();
    const ushort_t* cA = sA + cur * ASZ;
    const ushort_t* cB = sB + cur * BSZ;
#pragma unroll
    for (int ku = 0; ku < KU; ku++) {
      short8 af[MI], bf4[NI];
#pragma unroll
      for (int i = 0; i < MI; i++)
        af[i] = *(const short8*)(cA + (wr * (MT / 2) + i * 16 + lm) * BKT +
                                 ((ku * 4 + lq) ^ sw) * 8);
#pragma unroll
      for (int i = 0; i < NI; i++)
        bf4[i] = *(const short8*)(cB + (wc * (NT / 2) + i * 16 + lm) * BKT +
                                  ((ku * 4 + lq) ^ sw) * 8);
#pragma unroll
      for (int mt = 0; mt < MI; mt++)
#pragma unroll
        for (int nt = 0; nt < NI; nt++)
          acc[mt][nt] = __builtin_amdgcn_mfma_f32_16x16x32_bf16(
              af[mt], bf4[nt], acc[mt][nt], 0, 0, 0);
    }
    cur = nxt;
    nxt = (nxt == 2) ? 0 : nxt + 1;
  }

  // C/D layout (verified m89/m91): col = lane&15, row = (lane>>4)*4 + reg
#pragma unroll
  for (int mt = 0; mt < MI; mt++) {
    int rb = wr * (MT / 2) + mt * 16 + lq * 4;
#pragma unroll
    for (int nt = 0; nt < NI; nt++) {
      int c = wc * (NT / 2) + nt * 16 + lm;
#pragma unroll
      for (int r = 0; r < 4; r++) {
        size_t idx = (size_t)(rb + r) * ldc + c;
        if (EPI == 1) {
          Cb[idx] = f2bf(acc[mt][nt][r]);
        } else {
          float v = __tanf(acc[mt][nt][r] * ip[rb + r] * ic[c]);
          Cf0[idx] = v;
          Cf1[idx] = v;
        }
      }
    }
  }
}

// =====================================================================
// gemm_core2: double-buffered 2-phase via __syncthreads (known-good).
// Used by k3 (tbuf would cost its 2 blocks/CU: 3x32KB=96KB > 160/2).
// =====================================================================
template <int MT, int NT, int BKT, int EPI>
__device__ __forceinline__ void gemm_core2(
    const ushort_t* __restrict__ A, int lda,
    const ushort_t* __restrict__ B, int ldb,
    int K,
    ushort_t* sA, ushort_t* sB,
    ushort_t* Cb, float* Cf0, float* Cf1, int ldc,
    const float* __restrict__ ip, const float* __restrict__ ic) {
  constexpr int MI = MT / 32, NI = NT / 32, KU = BKT / 32;
  constexpr int LPR = BKT / 8;
  constexpr int RPC = 256 / LPR;
  constexpr int ASZ = MT * BKT, BSZ = NT * BKT;
  static_assert(LPR == 8, "swizzle assumes 8 segs per row");
  static_assert(RPC % 8 == 0, "row&7 must be per-lane constant");
  const int t = threadIdx.x;
  const int wave = t >> 6, lane = t & 63;
  const int lm = lane & 15, lq = lane >> 4;
  const int wr = wave >> 1, wc = wave & 1;

  f32x4 acc[MI][NI] = {};

  const int srow = t / LPR;
  const int gseg = (t % LPR) ^ (srow & 7);
  const ushort_t* ga = A + (size_t)srow * lda + gseg * 8;
  const ushort_t* gb = B + (size_t)srow * ldb + gseg * 8;
  const int sw = lm & 7;

  auto stage = [&](int k0, int buf) {
    ushort_t* dA = sA + buf * ASZ + wave * 512;
    ushort_t* dB = sB + buf * BSZ + wave * 512;
#pragma unroll
    for (int j = 0; j < MT / RPC; j++)
      async_cp16(ga + k0 + (size_t)j * RPC * lda, dA + j * 2048);
#pragma unroll
    for (int j = 0; j < NT / RPC; j++)
      async_cp16(gb + k0 + (size_t)j * RPC * ldb, dB + j * 2048);
  };

  stage(0, 0);
  int cur = 0;
  for (int k0 = 0; k0 < K; k0 += BKT) {
    __syncthreads();
    if (k0 + BKT < K) stage(k0 + BKT, cur ^ 1);
    const ushort_t* cA = sA + cur * ASZ;
    const ushort_t* cB = sB + cur * BSZ;
#pragma unroll
    for (int ku = 0; ku < KU; ku++) {
      short8 af[MI], bf4[NI];
#pragma unroll
      for (int i = 0; i < MI; i++)
        af[i] = *(const short8*)(cA + (wr * (MT / 2) + i * 16 + lm) * BKT +
                                 ((ku * 4 + lq) ^ sw) * 8);
#pragma unroll
      for (int i = 0; i < NI; i++)
        bf4[i] = *(const short8*)(cB + (wc * (NT / 2) + i * 16 + lm) * BKT +
                                  ((ku * 4 + lq) ^ sw) * 8);
#pragma unroll
      for (int mt = 0; mt < MI; mt++)
#pragma unroll
        for (int nt = 0; nt < NI; nt++)
          acc[mt][nt] = __builtin_amdgcn_mfma_f32_16x16x32_bf16(
              af[mt], bf4[nt], acc[mt][nt], 0, 0, 0);
    }
    cur ^= 1;
  }

#pragma unroll
  for (int mt = 0; mt < MI; mt++) {
    int rb = wr * (MT / 2) + mt * 16 + lq * 4;
#pragma unroll
    for (int nt = 0; nt < NI; nt++) {
      int c = wc * (NT / 2) + nt * 16 + lm;
#pragma unroll
      for (int r = 0; r < 4; r++) {
        size_t idx = (size_t)(rb + r) * ldc + c;
        if (EPI == 1) {
          Cb[idx] = f2bf(acc[mt][nt][r]);
        } else {
          float v = __tanf(acc[mt][nt][r] * ip[rb + r] * ic[c]);
          Cf0[idx] = v;
          Cf1[idx] = v;
        }
      }
    }
  }
}

// =====================================================================
// convT body (device fn): 64x64 tile, read f32, write bf16 straight +
// bf16 transposed. tile[] passed in (shared by the merged prep kernel).
// =====================================================================
__device__ __forceinline__ void convT_body(
    float (*tile)[65], const float* __restrict__ in,
    ushort_t* __restrict__ outn, ushort_t* __restrict__ outt,
    int n, int r0, int c0) {
  const int t = threadIdx.x;
  const int cr = t >> 4;        // 0..15
  const int cc = (t & 15) * 4;  // 0..60
#pragma unroll
  for (int p = 0; p < 4; p++) {
    int r = cr + p * 16;
    float4 v = *(const float4*)(in + (size_t)(r0 + r) * n + c0 + cc);
    tile[r][cc + 0] = v.x; tile[r][cc + 1] = v.y;
    tile[r][cc + 2] = v.z; tile[r][cc + 3] = v.w;
    ushort4 o;
    o.x = f2bf(v.x); o.y = f2bf(v.y); o.z = f2bf(v.z); o.w = f2bf(v.w);
    *(ushort4*)(outn + (size_t)(r0 + r) * n + c0 + cc) = o;
  }
  __syncthreads();
#pragma unroll
  for (int p = 0; p < 4; p++) {
    int r = cr + p * 16;  // output row = c0 + r
    ushort4 o;
    o.x = f2bf(tile[cc + 0][r]); o.y = f2bf(tile[cc + 1][r]);
    o.z = f2bf(tile[cc + 2][r]); o.w = f2bf(tile[cc + 3][r]);
    *(ushort4*)(outt + (size_t)(c0 + r) * n + r0 + cc) = o;
  }
}

// =====================================================================
// prep: ONE launch replacing convT(adj) [4096 blocks] + convT(wt)
// [64 blocks] + xcvt [2048 blocks]. Block-range dispatch; bodies
// unchanged from the verified r2-r7 kernels. Branch is block-uniform.
// =====================================================================
__global__ __launch_bounds__(256) void prep(
    const float* __restrict__ adj, ushort_t* __restrict__ adj_bf,
    ushort_t* __restrict__ adj_t,
    const float* __restrict__ wt, ushort_t* __restrict__ wt_bf,
    ushort_t* __restrict__ wt_t,
    const float* __restrict__ pre, const float* __restrict__ cur,
    ushort_t* __restrict__ xbf) {
  __shared__ float tile[64][65];
  const int b = blockIdx.x;
  if (b < 4096) {
    convT_body(tile, adj, adj_bf, adj_t, 4096, (b >> 6) * 64, (b & 63) * 64);
  } else if (b < 4160) {
    const int bb = b - 4096;
    convT_body(tile, wt, wt_bf, wt_t, 512, (bb >> 3) * 64, (bb & 7) * 64);
  } else {
    const size_t i = ((size_t)(b - 4160) * 256 + threadIdx.x) * 8;
    const float* src = (i < (size_t)4096 * 512)
                           ? (pre + i)
                           : (cur + (i - (size_t)4096 * 512));
    float4 a = *(const float4*)(src);
    float4 c = *(const float4*)(src + 4);
    short8 o;
    o[0] = (short)f2bf(a.x); o[1] = (short)f2bf(a.y);
    o[2] = (short)f2bf(a.z); o[3] = (short)f2bf(a.w);
    o[4] = (short)f2bf(c.x); o[5] = (short)f2bf(c.y);
    o[6] = (short)f2bf(c.z); o[7] = (short)f2bf(c.w);
    *(short8*)(xbf + i) = o;
  }
}

// =====================================================================
// K1: pw_t[512 x 8192] = (concat(pre,cur) @ w)^T as NT GEMM.
// 64x128, BK=64, counted-vmcnt tbuf (72KB LDS, 2 blocks/CU), 512 blocks.
// =====================================================================
__global__ __launch_bounds__(256) void k1_gemm(
    const ushort_t* __restrict__ wt_t, const ushort_t* __restrict__ xbf,
    ushort_t* __restrict__ pw_t) {
  __shared__ __align__(16) ushort_t sA[3 * 64 * 64];
  __shared__ __align__(16) ushort_t sB[3 * 128 * 64];
  const int bm = blockIdx.x & 7, bn = blockIdx.x >> 3;
  const ushort_t* A = wt_t + (size_t)bm * 64 * 512;
  const ushort_t* B = xbf + (size_t)bn * 128 * 512;
  ushort_t* C = pw_t + (size_t)bm * 64 * 8192 + bn * 128;
  gemm_core3<64, 128, 64, 1>(A, 512, B, 512, 512, sA, sB, C, nullptr, nullptr,
                             8192, nullptr, nullptr);
}

// =====================================================================
// K2 fused: half0 pre_h = adj @ cur_w ; half1 cur_h = adj^T @ pre_w
// 128x64, BK=64, counted-vmcnt tbuf (72KB LDS, 2 blocks/CU), 512 blocks.
// =====================================================================
__global__ __launch_bounds__(256) void k2_gemm(
    const ushort_t* __restrict__ adj, const ushort_t* __restrict__ adj_t,
    const ushort_t* __restrict__ pw_t, ushort_t* __restrict__ pn) {
  __shared__ __align__(16) ushort_t sA[3 * 128 * 64];
  __shared__ __align__(16) ushort_t sB[3 * 64 * 64];
  const int b = blockIdx.x;
  const int xcd = b & 7, i = b >> 3;            // i in 0..63
  const int half = xcd & 1;
  const int bm = ((xcd >> 1) << 3) | (i & 7);   // 0..31
  const int bn = i >> 3;                        // 0..7
  const ushort_t* A = (half ? adj_t : adj) + (size_t)bm * 128 * 4096;
  const ushort_t* B = pw_t + (size_t)bn * 64 * 8192 + (half ? 0 : 4096);
  ushort_t* C = pn + (half ? (size_t)4096 * 512 : 0) +
                (size_t)bm * 128 * 512 + bn * 64;
  gemm_core3<128, 64, 64, 1>(A, 4096, B, 8192, 4096, sA, sB, C, nullptr,
                             nullptr, 512, nullptr, nullptr);
}

// =====================================================================
// invnorm: invn[row] = 1 / max(||pn[row]||, 1e-8), one wave per row
// =====================================================================
__global__ __launch_bounds__(256) void invnorm_kernel(
    const ushort_t* __restrict__ pn, float* __restrict__ invn) {
  const int t = threadIdx.x;
  const int wave = t >> 6, lane = t & 63;
  const size_t row = (size_t)blockIdx.x * 4 + wave;
  const ushort_t* p = pn + row * 512 + lane * 8;
  short8 v = *(const short8*)p;
  float s = 0.f;
#pragma unroll
  for (int i = 0; i < 8; i++) {
    float f = bf2f((ushort_t)v[i]);
    s += f * f;
  }
#pragma unroll
  for (int off = 32; off > 0; off >>= 1) s += __shfl_xor(s, off, 64);
  if (lane == 0) invn[row] = 1.0f / fmaxf(sqrtf(s), 1e-8f);
}

// =====================================================================
// K3: cos = (pre_h @ cur_h^T) * inv_i * inv_j, tan, dual f32 store.
// 128x128, BK=64, dbuf (64KB LDS, 2 blocks/CU), 1024 blocks.
// =====================================================================
__global__ __launch_bounds__(256) void k3_gemm(
    const ushort_t* __restrict__ pn, const float* __restrict__ invn,
    float* __restrict__ out) {
  __shared__ __align__(16) ushort_t sA[2 * 128 * 64];
  __shared__ __align__(16) ushort_t sB[2 * 128 * 64];
  const int bm = blockIdx.x & 31, bn = blockIdx.x >> 5;
  const ushort_t* A = pn + (size_t)bm * 128 * 512;
  const ushort_t* B = pn + (size_t)4096 * 512 + (size_t)bn * 128 * 512;
  float* C0 = out + (size_t)bm * 128 * 4096 + bn * 128;
  gemm_core2<128, 128, 64, 2>(A, 512, B, 512, 512, sA, sB, nullptr, C0,
                              C0 + (size_t)4096 * 4096, 4096,
                              invn + bm * 128, invn + 4096 + bn * 128);
}

// =====================================================================
extern "C" void kernel_launch(void* const* d_in, const int* in_sizes, int n_in,
                              void* d_out, int out_size, void* d_ws,
                              size_t ws_size, hipStream_t stream) {
  const float* pre = (const float*)d_in[0];   // [4096,512] f32
  const float* cur = (const float*)d_in[1];   // [4096,512] f32
  const float* adj = (const float*)d_in[2];   // [4096,4096] f32
  const float* wt  = (const float*)d_in[3];   // [512,512] f32
  float* out = (float*)d_out;                 // 2 x [4096,4096] f32

  // workspace layout (~93 MB)
  ushort_t* adj_bf = (ushort_t*)d_ws;                       // 4096*4096
  ushort_t* adj_t  = adj_bf + (size_t)4096 * 4096;          // 4096*4096
  ushort_t* pw_t   = adj_t + (size_t)4096 * 4096;           // 512*8192
  ushort_t* pn     = pw_t + (size_t)512 * 8192;             // 8192*512
  ushort_t* wt_t   = pn + (size_t)8192 * 512;               // 512*512
  ushort_t* wt_bf  = wt_t + (size_t)512 * 512;              // 512*512 (dummy)
  float*    invn   = (float*)(wt_bf + (size_t)512 * 512);   // 8192 f32
  ushort_t* xbf    = (ushort_t*)(invn + 8192);              // 8192*512

  prep<<<6208, 256, 0, stream>>>(adj, adj_bf, adj_t, wt, wt_bf, wt_t,
                                 pre, cur, xbf);
  k1_gemm<<<512, 256, 0, stream>>>(wt_t, xbf, pw_t);
  k2_gemm<<<512, 256, 0, stream>>>(adj_bf, adj_t, pw_t, pn);
  invnorm_kernel<<<2048, 256, 0, stream>>>(pn, invn);
  k3_gemm<<<1024, 256, 0, stream>>>(pn, invn, out);
}